// Round 8
// baseline (1370.437 us; speedup 1.0000x reference)
//
#include <hip/hip_runtime.h>
#include <hip/hip_bf16.h>

#define NTOK 511
#define NINT 255

typedef unsigned short u16;
typedef __attribute__((ext_vector_type(8))) short bf16x8;
typedef __attribute__((ext_vector_type(4))) float f32x4;

// ---- workspace layout (float offsets) ----
constexpr int OFF_FLAG = 0;                 // [0] dtype flag
constexpr int OFF_WB   = 4;                 // bf16 weight region
constexpr int W3B = 294912;                 // leaf W3: [jc][ks] 8x4x512 = 16384
constexpr int WB_ELEMS = 311296;
constexpr int OFF_BIAS = OFF_WB + WB_ELEMS / 2;
constexpr int BW4 = 0, BUB4 = 512, BUB1 = 1024, BUU4 = 1152, B3 = 1664;
constexpr int BIAS_FLOATS = 1792;
constexpr int OFF_ROOT  = OFF_BIAS + BIAS_FLOATS;   // rootH 32768 + rootC 32768 (fp32)
constexpr int OFF_SORT  = OFF_ROOT + 65536;         // cnt[8],curB[8],curU[8], perm[Bc*255], inv[Bc*255]
constexpr long PER_TREE = 49152;            // floats: Ha bf16 + Hb bf16 + Ca f32 + Cb f32

// h buffers in MFMA-A-fragment order keyed by SORTED parent slot:
//   h[tile][ks][lane][8] bf16, tile = slot>>4, with slot = inv_level[parent node].
// Consumer (whose tiles are 16 consecutive sorted slots) reads ah[ks] as ONE
// coalesced 1KB load. Producer scatter-stores via stH2 (write path, latency-insensitive).

__device__ __forceinline__ float bf2f(__hip_bfloat16 v) { return __bfloat162float(v); }
__device__ __forceinline__ short f2s(float f) {
    __hip_bfloat16 b = __float2bfloat16(f);
    return *reinterpret_cast<short*>(&b);
}
__device__ __forceinline__ float sigm(float x) { return 1.0f / (1.0f + __expf(-x)); }
__device__ __forceinline__ float tanh_(float x) { return 1.0f - 2.0f / (__expf(2.0f * x) + 1.0f); }

__device__ __forceinline__ float ldf(const void* p, long idx, int isbf) {
    return isbf ? bf2f(((const __hip_bfloat16*)p)[idx]) : ((const float*)p)[idx];
}

__device__ __forceinline__ bf16x8 ldA(const void* p, long idx, int isbf) {
    if (isbf) return *(const bf16x8*)((const short*)p + idx);
    const float* f = (const float*)p + idx;
    float4 a = *(const float4*)f, b = *(const float4*)(f + 4);
    bf16x8 r;
    r[0] = f2s(a.x); r[1] = f2s(a.y); r[2] = f2s(a.z); r[3] = f2s(a.w);
    r[4] = f2s(b.x); r[5] = f2s(b.y); r[6] = f2s(b.z); r[7] = f2s(b.w);
    return r;
}

// async global->LDS 16B
typedef const __attribute__((address_space(1))) unsigned int* gp1_t;
typedef __attribute__((address_space(3))) unsigned int* lp3_t;
__device__ __forceinline__ void stage16(const void* g, void* l) {
    __builtin_amdgcn_global_load_lds((gp1_t)g, (lp3_t)l, 16, 0, 0);
}

// ---- dtype detection ----
__global__ void detect_kernel(const void* W, float* ws) {
    if (threadIdx.x == 0 && blockIdx.x == 0) {
        const u16* u = (const u16*)W;
        int cnt = 0;
        for (int i = 0; i < 128; i += 2) {
            u16 x = u[i];
            int ex = (x >> 7) & 0xff;
            if (x == 0 || (ex >= 96 && ex <= 127)) cnt++;
        }
        ((int*)ws)[0] = (cnt >= 48) ? 1 : 0;
    }
}

// ---- arity-bucket sort: per level, binaries first. Order within bucket is
//      arbitrary (atomic) — any permutation is mathematically identical. ----
__global__ void sort_zero(float* ws) {
    if (threadIdx.x < 24) ((int*)(ws + OFF_SORT))[threadIdx.x] = 0;
}
__global__ __launch_bounds__(256) void sort_count(const int* __restrict__ arity,
                                                  float* ws, int treeOff, int Bc) {
    int* cnt = (int*)(ws + OFF_SORT);
    int total = Bc * 255;
    for (int idx = blockIdx.x * 256 + threadIdx.x; idx < total; idx += gridDim.x * 256) {
        int rem = idx, l = 0;
        while (rem >= (Bc << l)) { rem -= (Bc << l); ++l; }
        int p = rem, blt = p >> l, i = p - (blt << l);
        int ar = arity[(long)(treeOff + blt) * NINT + (1 << l) - 1 + i];
        if (ar == 1) atomicAdd(&cnt[l], 1);
    }
}
__global__ __launch_bounds__(256) void sort_place(const int* __restrict__ arity,
                                                  float* ws, int treeOff, int Bc) {
    int* cnt = (int*)(ws + OFF_SORT);
    int* curB = cnt + 8; int* curU = cnt + 16;
    int* permB = cnt + 24;
    int* invB = permB + Bc * 255;
    int total = Bc * 255;
    for (int idx = blockIdx.x * 256 + threadIdx.x; idx < total; idx += gridDim.x * 256) {
        int rem = idx, l = 0;
        while (rem >= (Bc << l)) { rem -= (Bc << l); ++l; }
        int p = rem, blt = p >> l, i = p - (blt << l);
        int ar = arity[(long)(treeOff + blt) * NINT + (1 << l) - 1 + i];
        int base = Bc * ((1 << l) - 1);
        int spos;
        if (ar == 1) spos = atomicAdd(&curB[l], 1);
        else         spos = cnt[l] + atomicAdd(&curU[l], 1);
        permB[base + spos] = p;
        invB[base + p] = spos;
    }
}

// ---- repack: raw weights -> bf16 jc-major frag-linear + fp32 biases ----
__global__ __launch_bounds__(256) void repack_mfma(
    const void* W, const void* bW, const void* Ubin, const void* bUbin,
    const void* Uun, const void* bUun, float* ws)
{
    const int isbf = ((const int*)ws)[0];
    short* wb = (short*)(ws + OFF_WB);
    float* bias = ws + OFF_BIAS;
    int tid = blockIdx.x * blockDim.x + threadIdx.x;
    int nth = gridDim.x * blockDim.x;

    for (int idx = tid; idx < 294912; idx += nth) {
        int e = idx & 511, fjc = idx >> 9;
        int jc = fjc / 72, f = fjc - jc * 72;
        int lane = e >> 3, id8 = e & 7;
        int j = jc * 16 + (lane & 15);
        float v;
        if (f < 16) {
            int g = f >> 2, ks = f & 3;
            int k = ks * 32 + (lane >> 4) * 8 + id8;
            v = ldf(W, (long)g * 16384 + k * 128 + j, isbf);
        } else if (f < 32) {
            int fu = f - 16; int g = fu >> 2, ks = fu & 3;
            int k = ks * 32 + (lane >> 4) * 8 + id8;
            v = ldf(Uun, (long)g * 16384 + k * 128 + j, isbf);
        } else {
            int fb = f - 32; int g = fb >> 3, ks = fb & 7;
            int k = ks * 32 + (lane >> 4) * 8 + id8;
            v = ldf(Ubin, (long)g * 32768 + k * 128 + j, isbf);
        }
        wb[idx] = f2s(v);
    }
    for (int idx = tid; idx < 16384; idx += nth) {
        int e = idx & 511, frag = idx >> 9;
        int jc = frag >> 2, ks = frag & 3;
        int lane = e >> 3, id8 = e & 7;
        int k = ks * 32 + (lane >> 4) * 8 + id8;
        int j = jc * 16 + (lane & 15);
        wb[W3B + idx] = f2s(ldf(W, (long)3 * 16384 + k * 128 + j, isbf));
    }
    for (int j = tid; j < 128; j += nth) {
        float4 b;
        b.x = ldf(bW, 0 * 128 + j, isbf); b.y = ldf(bW, 1 * 128 + j, isbf);
        b.z = ldf(bW, 2 * 128 + j, isbf); b.w = ldf(bW, 3 * 128 + j, isbf);
        ((float4*)(bias + BW4))[j] = b;
        float4 bb;
        bb.x = ldf(bUbin, 0 * 128 + j, isbf); bb.y = ldf(bUbin, 1 * 128 + j, isbf);
        bb.z = ldf(bUbin, 2 * 128 + j, isbf); bb.w = ldf(bUbin, 3 * 128 + j, isbf);
        ((float4*)(bias + BUB4))[j] = bb;
        (bias + BUB1)[j] = ldf(bUbin, 4 * 128 + j, isbf);
        float4 bu;
        bu.x = ldf(bUun, 0 * 128 + j, isbf); bu.y = ldf(bUun, 1 * 128 + j, isbf);
        bu.z = ldf(bUun, 2 * 128 + j, isbf); bu.w = ldf(bUun, 3 * 128 + j, isbf);
        ((float4*)(bias + BUU4))[j] = bu;
        (bias + B3)[j] = ldf(bW, 3 * 128 + j, isbf);
    }
}

#define MFMA(A, B, C) __builtin_amdgcn_mfma_f32_16x16x32_bf16(A, B, C, 0, 0, 0)

// frag-layout h store by SORTED slot
__device__ __forceinline__ void stH2(short* __restrict__ hOut, int slot, int side, int j, short hs) {
    int k0 = side * 128 + j;
    long addr = (((long)(slot >> 4) * 8 + (k0 >> 5)) << 9)
              + ((((k0 >> 3) & 3) * 16 + (slot & 15)) << 3) + (k0 & 7);
    hOut[addr] = hs;
}

// ---- leaf: h = tanh(x @ W3 + b3); stores h at slot inv7[parent] ----
__global__ __launch_bounds__(256, 2) void leaf_mfma(
    const int* __restrict__ tokens, const void* emb, const float* __restrict__ ws,
    short* __restrict__ hOut, const int* __restrict__ inv7,
    int treeOff, int Mtot, int iters)
{
    const int t = threadIdx.x;
    const int isbf = ((const int*)ws)[0];
    const int wv = t >> 6, lane = t & 63, quad = lane >> 4, l16 = lane & 15;
    const short* wb = (const short*)(ws + OFF_WB);
    const float* bias = ws + OFF_BIAS;

    bf16x8 bf[32];
#pragma unroll
    for (int f = 0; f < 32; ++f)
        bf[f] = *(const bf16x8*)(wb + W3B + f * 512 + lane * 8);
    float b3v[8];
#pragma unroll
    for (int jc = 0; jc < 8; ++jc) b3v[jc] = (bias + B3)[jc * 16 + l16];

    for (int it = 0; it < iters; ++it) {
        int rb = (blockIdx.x * iters + it) * 64 + wv * 16;
        if (rb >= Mtot) break;
        int p = rb + l16; if (p >= Mtot) p = Mtot - 1;
        int bl = p >> 8, i = p & 255;
        int tk = tokens[(long)(treeOff + bl) * NTOK + 255 + i];
        bf16x8 ax[4];
#pragma unroll
        for (int ks = 0; ks < 4; ++ks)
            ax[ks] = ldA(emb, (long)tk * 128 + ks * 32 + quad * 8, isbf);
        // sorted slots for the 4 output nodes (hoisted, reused across jc)
        int sp4[4], sd4[4];
#pragma unroll
        for (int r = 0; r < 4; ++r) {
            int cn = rb + quad * 4 + r;
            sp4[r] = inv7[cn >> 1]; sd4[r] = cn & 1;
        }
        f32x4 acc[8];
#pragma unroll
        for (int jc = 0; jc < 8; ++jc) acc[jc] = {0.f, 0.f, 0.f, 0.f};
#pragma unroll
        for (int jc = 0; jc < 8; ++jc)
#pragma unroll
            for (int ks = 0; ks < 4; ++ks)
                acc[jc] = MFMA(ax[ks], bf[jc * 4 + ks], acc[jc]);
#pragma unroll
        for (int jc = 0; jc < 8; ++jc)
#pragma unroll
            for (int r = 0; r < 4; ++r)
                stH2(hOut, sp4[r], sd4[r], jc * 16 + l16, f2s(tanh_(acc[jc][r] + b3v[jc])));
    }
}

// ---- unified level kernel: 512 threads, one jc per block, 72KB staged once,
//      barrier-free q-loop, ARITY-UNIFORM sorted tiles skip Uu or Ub. ----
__global__ __launch_bounds__(512, 4) void level8_mfma(
    const int* __restrict__ tokens, const int* __restrict__ arity, const void* emb,
    const float* __restrict__ ws, const short* __restrict__ hChild,
    const float* __restrict__ cChild, short* __restrict__ hOut, float* __restrict__ cOut,
    float* __restrict__ rootH, float* __restrict__ rootC,
    const int* __restrict__ perm, const int* __restrict__ invN,
    int lvl, int treeOff, int leafchild, int isRoot, int Mtot, int Mchild,
    int NBMB, int Q)
{
    __shared__ short Bs[72 * 512];          // 72 KB: full jc weight slice

    const int t = threadIdx.x;
    const int isbf = ((const int*)ws)[0];
    const int jc = blockIdx.x / NBMB;
    const int mb = blockIdx.x - jc * NBMB;
    const int wv = t >> 6, lane = t & 63, quad = lane >> 4, l16 = lane & 15;
    const int cnt = 1 << lvl, o2 = cnt - 1;
    const short* wb = (const short*)(ws + OFF_WB);
    const float* bias = ws + OFF_BIAS;
    const short* wj = wb + (long)jc * 36864;
    const int j = jc * 16 + l16;

    // stage the full 72 KB slice once
#pragma unroll
    for (int s = 0; s < 9; ++s) {
        int off = (s * 512 + t) * 8;
        stage16(wj + off, Bs + off);
    }
    __syncthreads();   // weights resident; only barrier in the kernel

    for (int q = 0; q < Q; ++q) {
        const int p0 = (mb * Q + q) * 128;
        if (p0 >= Mtot) break;

        // ---- sorted-slot row -> node via perm ----
        int row = wv * 16 + l16;
        int spos = p0 + row; if (spos >= Mtot) spos = Mtot - 1;
        int p = perm[spos];
        int bl = p >> lvl, i = p - (bl << lvl);
        int tk = tokens[(long)(treeOff + bl) * NTOK + o2 + i];

        // epilogue rows: node, arity, child c (issued early; hidden under MFMA)
        int pnode[4], arv[4]; float clv[4], crv[4];
#pragma unroll
        for (int r = 0; r < 4; ++r) {
            int se = p0 + wv * 16 + quad * 4 + r;
            if (se >= Mtot) se = Mtot - 1;
            int pe = perm[se];
            pnode[r] = pe;
            int ble = pe >> lvl, ie = pe - (ble << lvl);
            arv[r] = arity[(long)(treeOff + ble) * NINT + o2 + ie];
            if (!leafchild) {
                long crowe = (long)ble * (cnt << 1) + 2 * ie;
                clv[r] = cChild[((long)jc * Mchild + crowe) * 16 + l16];
                crv[r] = cChild[((long)jc * Mchild + crowe + 1) * 16 + l16];
            } else { clv[r] = 0.f; crv[r] = 0.f; }
        }

        // A-fragments: ah coalesced from sorted tile (no perm dependency)
        const short* hT = hChild + (((long)(p0 >> 4) + wv) << 12);
        bf16x8 ax[4], ah[8];
#pragma unroll
        for (int ks = 0; ks < 8; ++ks)
            ah[ks] = *(const bf16x8*)(hT + ks * 512 + lane * 8);
#pragma unroll
        for (int ks = 0; ks < 4; ++ks)
            ax[ks] = ldA(emb, (long)tk * 128 + ks * 32 + quad * 8, isbf);

        // tile arity flags (wave-uniform; boundary tile runs both paths)
        unsigned long long b0 = __ballot(arv[0] == 1);
        unsigned long long b1 = __ballot(arv[1] == 1);
        unsigned long long b2 = __ballot(arv[2] == 1);
        unsigned long long b3 = __ballot(arv[3] == 1);
        bool doUb = (b0 | b1 | b2 | b3) != 0ULL;
        bool doUu = (b0 & b1 & b2 & b3) != ~0ULL;

        f32x4 aW[4], aU[4], aB[5];
#pragma unroll
        for (int g = 0; g < 4; ++g) { aW[g] = {0,0,0,0}; aU[g] = {0,0,0,0}; }
#pragma unroll
        for (int g = 0; g < 5; ++g) aB[g] = {0,0,0,0};

        // Ub first (ah-dependent, hides the perm->tok->emb chain for ax)
        if (doUb) {
#pragma unroll
            for (int f = 32; f < 72; ++f) {
                bf16x8 b = *(const bf16x8*)&Bs[f * 512 + lane * 8];
                int fb = f - 32;
                aB[fb >> 3] = MFMA(ah[fb & 7], b, aB[fb >> 3]);
            }
        }
        if (doUu) {
#pragma unroll
            for (int f = 16; f < 32; ++f) {
                bf16x8 b = *(const bf16x8*)&Bs[f * 512 + lane * 8];
                aU[(f - 16) >> 2] = MFMA(ah[(f - 16) & 3], b, aU[(f - 16) >> 2]);
            }
        }
#pragma unroll
        for (int f = 0; f < 16; ++f) {
            bf16x8 b = *(const bf16x8*)&Bs[f * 512 + lane * 8];
            aW[f >> 2] = MFMA(ax[f & 3], b, aW[f >> 2]);
        }

        // biases late (uniform per jc, L2-hot)
        const float4 bw = ((const float4*)(bias + BW4))[j];
        const float4 bb = ((const float4*)(bias + BUB4))[j];
        const float  b1f = (bias + BUB1)[j];
        const float4 bu = ((const float4*)(bias + BUU4))[j];

        // ---- epilogue ----
#pragma unroll
        for (int r = 0; r < 4; ++r) {
            int se = p0 + wv * 16 + quad * 4 + r;
            bool val = (se < Mtot);
            int pc = pnode[r];
            bool bin = (arv[r] == 1);
            float w0 = aW[0][r] + bw.x;
            float w1 = aW[1][r] + bw.y;
            float w2 = aW[2][r] + bw.z;
            float w3 = aW[3][r] + bw.w;
            float pi, pf, po, pu;
            if (bin) { pi = w0 + aB[0][r] + bb.x; pf = w1 + aB[1][r] + bb.y;
                       po = w2 + aB[3][r] + bb.w; pu = w3 + aB[4][r] + b1f; }
            else     { pi = w0 + aU[0][r] + bu.x; pf = w1 + aU[1][r] + bu.y;
                       po = w2 + aU[2][r] + bu.z; pu = w3 + aU[3][r] + bu.w; }
            float cl = clv[r];
            float cr = bin ? crv[r] : 0.f;
            float frv = bin ? sigm(w1 + aB[2][r] + bb.z) : 0.f;
            float ig = sigm(pi), fg = sigm(pf), og = sigm(po), ug = tanh_(pu);
            float c = ig * ug + fg * cl + frv * cr;
            float h = og * tanh_(c);
            if (isRoot) {
                if (val) {
                    int ble = pc >> lvl;
                    rootH[(long)(treeOff + ble) * 128 + j] = h;
                    rootC[(long)(treeOff + ble) * 128 + j] = c;
                }
            } else if (val) {
                cOut[((long)jc * Mtot + pc) * 16 + l16] = c;
                stH2(hOut, invN[pc >> 1], pc & 1, j, f2s(h));
            }
        }
    }
}

// ---- output: rootH/rootC fp32 -> d_out ----
__global__ __launch_bounds__(256) void out_kernel(const float* ws, void* out)
{
    const int isbf = ((const int*)ws)[0];
    const float* rootH = ws + OFF_ROOT;
    const float* rootC = rootH + 32768;
    int t = blockIdx.x * 256 + threadIdx.x;
    float h = rootH[t], c = rootC[t];
    if (isbf) {
        ((__hip_bfloat16*)out)[t]         = __float2bfloat16(h);
        ((__hip_bfloat16*)out)[32768 + t] = __float2bfloat16(c);
    } else {
        ((float*)out)[t]         = h;
        ((float*)out)[32768 + t] = c;
    }
}

extern "C" void kernel_launch(void* const* d_in, const int* in_sizes, int n_in,
                              void* d_out, int out_size, void* d_ws, size_t ws_size,
                              hipStream_t stream)
{
    const int* tokens = (const int*)d_in[0];
    const int* arity  = (const int*)d_in[1];
    const void* emb   = d_in[2];
    const void* W     = d_in[3];
    const void* bW    = d_in[4];
    const void* Ubin  = d_in[5];
    const void* bUbin = d_in[6];
    const void* Uun   = d_in[7];
    const void* bUun  = d_in[8];

    float* ws = (float*)d_ws;

    int Bc = 256;
    while (Bc > 1 &&
           (size_t)((long)OFF_SORT + 24 + 2L * Bc * 255 + (long)Bc * PER_TREE) * 4 > ws_size)
        Bc >>= 1;
    const int nCh = 256 / Bc;
    const long offChunk = (long)OFF_SORT + 24 + 2L * Bc * 255;

    detect_kernel<<<1, 64, 0, stream>>>(W, ws);
    repack_mfma<<<128, 256, 0, stream>>>(W, bW, Ubin, bUbin, Uun, bUun, ws);

    int* permB = (int*)(ws + OFF_SORT) + 24;
    int* invB  = permB + Bc * 255;
    short* Ha = (short*)(ws + offChunk);
    short* Hb = Ha + (long)Bc * 32768;
    float* Ca = (float*)(Hb + (long)Bc * 16384);
    float* Cb = Ca + (long)Bc * 8192;
    float* rootH = ws + OFF_ROOT;
    float* rootC = rootH + 32768;

    for (int cidx = 0; cidx < nCh; ++cidx) {
        int toff = cidx * Bc;
        // arity bucket tables for this chunk
        sort_zero<<<1, 32, 0, stream>>>(ws);
        sort_count<<<128, 256, 0, stream>>>(arity, ws, toff, Bc);
        sort_place<<<128, 256, 0, stream>>>(arity, ws, toff, Bc);
        {
            int Mleaf = Bc * 256;
            int NBL = (Mleaf + 63) / 64; if (NBL > 512) NBL = 512;
            int itersL = (Mleaf + NBL * 64 - 1) / (NBL * 64);
            const int* inv7 = invB + Bc * 127;
            leaf_mfma<<<NBL, 256, 0, stream>>>(tokens, emb, ws, Ha, inv7, toff, Mleaf, itersL);
        }
        for (int l = 7; l >= 0; --l) {
            int M = Bc << l;
            int Mchild = Bc << (l + 1);
            const short* hC = (l & 1) ? Ha : Hb;
            const float* cC = (l & 1) ? Ca : Cb;
            short* hO = (l & 1) ? Hb : Ha;
            float* cO = (l & 1) ? Cb : Ca;
            int lc = (l == 7) ? 1 : 0;
            int isRoot = (l == 0) ? 1 : 0;
            const int* permL = permB + Bc * ((1 << l) - 1);
            const int* invN  = (l > 0) ? invB + Bc * ((1 << (l - 1)) - 1) : invB;
            int NBM = (M + 127) / 128;
            int Q = NBM / 64; if (Q < 1) Q = 1;
            int NBMB = (NBM + Q - 1) / Q;
            level8_mfma<<<dim3(NBMB * 8), 512, 0, stream>>>(
                tokens, arity, emb, ws, hC, cC, hO, cO, rootH, rootC,
                permL, invN, l, toff, lc, isRoot, M, Mchild, NBMB, Q);
        }
    }
    out_kernel<<<128, 256, 0, stream>>>(ws, d_out);
}

// Round 9
// 179.358 us; speedup vs baseline: 7.6408x; 7.6408x over previous
//
#include <hip/hip_runtime.h>
#include <hip/hip_bf16.h>

#define NTOK 511
#define NINT 255

typedef unsigned short u16;
typedef __attribute__((ext_vector_type(8))) short bf16x8;
typedef __attribute__((ext_vector_type(4))) float f32x4;

// ---- workspace layout (float offsets) ----
constexpr int OFF_FLAG = 0;                 // [0] dtype flag
constexpr int OFF_WB   = 4;                 // bf16 weight region
constexpr int W3B = 294912;                 // leaf W3: [jc][ks] 8x4x512 = 16384
constexpr int WB_ELEMS = 311296;
constexpr int OFF_BIAS = OFF_WB + WB_ELEMS / 2;
constexpr int BW4 = 0, BUB4 = 512, BUB1 = 1024, BUU4 = 1152, B3 = 1664;
constexpr int BIAS_FLOATS = 1792;
constexpr int OFF_ROOT  = OFF_BIAS + BIAS_FLOATS;   // rootH 32768 + rootC 32768 (fp32)
constexpr int OFF_SORT  = OFF_ROOT + 65536;         // curB[8],curU[8],spare[8], perm[Bc*255], inv[Bc*255]
constexpr long PER_TREE = 49152;            // floats: Ha bf16 + Hb bf16 + Ca f32 + Cb f32

// h buffers in MFMA-A-fragment order keyed by SORTED parent slot:
//   h[tile][ks][lane][8] bf16, tile = slot>>4, with slot = inv_level[parent node].
// Consumer (whose tiles are 16 consecutive sorted slots) reads ah[ks] as ONE
// coalesced 1KB load. Producer scatter-stores via stH2 (write path, latency-insensitive).

__device__ __forceinline__ float bf2f(__hip_bfloat16 v) { return __bfloat162float(v); }
__device__ __forceinline__ short f2s(float f) {
    __hip_bfloat16 b = __float2bfloat16(f);
    return *reinterpret_cast<short*>(&b);
}
__device__ __forceinline__ float sigm(float x) { return 1.0f / (1.0f + __expf(-x)); }
__device__ __forceinline__ float tanh_(float x) { return 1.0f - 2.0f / (__expf(2.0f * x) + 1.0f); }

__device__ __forceinline__ float ldf(const void* p, long idx, int isbf) {
    return isbf ? bf2f(((const __hip_bfloat16*)p)[idx]) : ((const float*)p)[idx];
}

__device__ __forceinline__ bf16x8 ldA(const void* p, long idx, int isbf) {
    if (isbf) return *(const bf16x8*)((const short*)p + idx);
    const float* f = (const float*)p + idx;
    float4 a = *(const float4*)f, b = *(const float4*)(f + 4);
    bf16x8 r;
    r[0] = f2s(a.x); r[1] = f2s(a.y); r[2] = f2s(a.z); r[3] = f2s(a.w);
    r[4] = f2s(b.x); r[5] = f2s(b.y); r[6] = f2s(b.z); r[7] = f2s(b.w);
    return r;
}

// async global->LDS 16B
typedef const __attribute__((address_space(1))) unsigned int* gp1_t;
typedef __attribute__((address_space(3))) unsigned int* lp3_t;
__device__ __forceinline__ void stage16(const void* g, void* l) {
    __builtin_amdgcn_global_load_lds((gp1_t)g, (lp3_t)l, 16, 0, 0);
}

// ---- dtype detection ----
__global__ void detect_kernel(const void* W, float* ws) {
    if (threadIdx.x == 0 && blockIdx.x == 0) {
        const u16* u = (const u16*)W;
        int cnt = 0;
        for (int i = 0; i < 128; i += 2) {
            u16 x = u[i];
            int ex = (x >> 7) & 0xff;
            if (x == 0 || (ex >= 96 && ex <= 127)) cnt++;
        }
        ((int*)ws)[0] = (cnt >= 48) ? 1 : 0;
    }
}

// ---- arity-bucket tables: binaries ascending from 0, unaries DESCENDING
//      from n-1 (no count pass needed). Block-aggregated atomics:
//      ballot/popc lane ranks + LDS wave-prefix + ONE atomicAdd per
//      category per block-chunk (~500 total vs 130K per-thread). Order
//      within a bucket is arbitrary -> atomic order nondeterminism is safe. ----
__global__ void sort_zero(float* ws) {
    if (threadIdx.x < 24) ((int*)(ws + OFF_SORT))[threadIdx.x] = 0;
}
__global__ __launch_bounds__(256) void sort_place(const int* __restrict__ arity,
                                                  float* ws, int treeOff, int Bc) {
    __shared__ int wB[4], wU[4], sB, sU;
    int* cnt = (int*)(ws + OFF_SORT);
    int* curB = cnt; int* curU = cnt + 8;
    int* permB = cnt + 24;
    int* invB = permB + Bc * 255;
    const int t = threadIdx.x, wv = t >> 6, lane = t & 63;
    const unsigned long long ltm = (1ull << lane) - 1;

    for (int l = 0; l < 8; ++l) {
        int n = Bc << l;
        int base = Bc * ((1 << l) - 1);
        for (int p0 = blockIdx.x * 256; p0 < n; p0 += gridDim.x * 256) {
            int p = p0 + t;
            bool act = (p < n);
            int ar = 0;
            if (act) {
                int blt = p >> l, i = p - (blt << l);
                ar = arity[(long)(treeOff + blt) * NINT + (1 << l) - 1 + i];
            }
            bool bin = act && (ar == 1);
            unsigned long long mb = __ballot(bin);
            unsigned long long ma = __ballot(act);
            unsigned long long mu = ma & ~mb;
            int nB = __popcll(mb), nU = __popcll(mu);
            if (lane == 0) { wB[wv] = nB; wU[wv] = nU; }
            __syncthreads();
            if (t == 0) {
                int tB = wB[0] + wB[1] + wB[2] + wB[3];
                int tU = wU[0] + wU[1] + wU[2] + wU[3];
                sB = atomicAdd(&curB[l], tB);
                sU = atomicAdd(&curU[l], tU);
            }
            __syncthreads();
            int preB = sB, preU = sU;
            for (int w = 0; w < wv; ++w) { preB += wB[w]; preU += wU[w]; }
            if (act) {
                int spos;
                if (bin) spos = preB + __popcll(mb & ltm);
                else     spos = n - 1 - (preU + __popcll(mu & ltm));
                permB[base + spos] = p;
                invB[base + p] = spos;
            }
            __syncthreads();   // wB/wU reuse
        }
    }
}

// ---- repack: raw weights -> bf16 jc-major frag-linear + fp32 biases ----
__global__ __launch_bounds__(256) void repack_mfma(
    const void* W, const void* bW, const void* Ubin, const void* bUbin,
    const void* Uun, const void* bUun, float* ws)
{
    const int isbf = ((const int*)ws)[0];
    short* wb = (short*)(ws + OFF_WB);
    float* bias = ws + OFF_BIAS;
    int tid = blockIdx.x * blockDim.x + threadIdx.x;
    int nth = gridDim.x * blockDim.x;

    for (int idx = tid; idx < 294912; idx += nth) {
        int e = idx & 511, fjc = idx >> 9;
        int jc = fjc / 72, f = fjc - jc * 72;
        int lane = e >> 3, id8 = e & 7;
        int j = jc * 16 + (lane & 15);
        float v;
        if (f < 16) {
            int g = f >> 2, ks = f & 3;
            int k = ks * 32 + (lane >> 4) * 8 + id8;
            v = ldf(W, (long)g * 16384 + k * 128 + j, isbf);
        } else if (f < 32) {
            int fu = f - 16; int g = fu >> 2, ks = fu & 3;
            int k = ks * 32 + (lane >> 4) * 8 + id8;
            v = ldf(Uun, (long)g * 16384 + k * 128 + j, isbf);
        } else {
            int fb = f - 32; int g = fb >> 3, ks = fb & 7;
            int k = ks * 32 + (lane >> 4) * 8 + id8;
            v = ldf(Ubin, (long)g * 32768 + k * 128 + j, isbf);
        }
        wb[idx] = f2s(v);
    }
    for (int idx = tid; idx < 16384; idx += nth) {
        int e = idx & 511, frag = idx >> 9;
        int jc = frag >> 2, ks = frag & 3;
        int lane = e >> 3, id8 = e & 7;
        int k = ks * 32 + (lane >> 4) * 8 + id8;
        int j = jc * 16 + (lane & 15);
        wb[W3B + idx] = f2s(ldf(W, (long)3 * 16384 + k * 128 + j, isbf));
    }
    for (int j = tid; j < 128; j += nth) {
        float4 b;
        b.x = ldf(bW, 0 * 128 + j, isbf); b.y = ldf(bW, 1 * 128 + j, isbf);
        b.z = ldf(bW, 2 * 128 + j, isbf); b.w = ldf(bW, 3 * 128 + j, isbf);
        ((float4*)(bias + BW4))[j] = b;
        float4 bb;
        bb.x = ldf(bUbin, 0 * 128 + j, isbf); bb.y = ldf(bUbin, 1 * 128 + j, isbf);
        bb.z = ldf(bUbin, 2 * 128 + j, isbf); bb.w = ldf(bUbin, 3 * 128 + j, isbf);
        ((float4*)(bias + BUB4))[j] = bb;
        (bias + BUB1)[j] = ldf(bUbin, 4 * 128 + j, isbf);
        float4 bu;
        bu.x = ldf(bUun, 0 * 128 + j, isbf); bu.y = ldf(bUun, 1 * 128 + j, isbf);
        bu.z = ldf(bUun, 2 * 128 + j, isbf); bu.w = ldf(bUun, 3 * 128 + j, isbf);
        ((float4*)(bias + BUU4))[j] = bu;
        (bias + B3)[j] = ldf(bW, 3 * 128 + j, isbf);
    }
}

#define MFMA(A, B, C) __builtin_amdgcn_mfma_f32_16x16x32_bf16(A, B, C, 0, 0, 0)

// frag-layout h store by SORTED slot
__device__ __forceinline__ void stH2(short* __restrict__ hOut, int slot, int side, int j, short hs) {
    int k0 = side * 128 + j;
    long addr = (((long)(slot >> 4) * 8 + (k0 >> 5)) << 9)
              + ((((k0 >> 3) & 3) * 16 + (slot & 15)) << 3) + (k0 & 7);
    hOut[addr] = hs;
}

// ---- leaf: h = tanh(x @ W3 + b3); stores h at slot inv7[parent] ----
__global__ __launch_bounds__(256, 2) void leaf_mfma(
    const int* __restrict__ tokens, const void* emb, const float* __restrict__ ws,
    short* __restrict__ hOut, const int* __restrict__ inv7,
    int treeOff, int Mtot, int iters)
{
    const int t = threadIdx.x;
    const int isbf = ((const int*)ws)[0];
    const int wv = t >> 6, lane = t & 63, quad = lane >> 4, l16 = lane & 15;
    const short* wb = (const short*)(ws + OFF_WB);
    const float* bias = ws + OFF_BIAS;

    bf16x8 bf[32];
#pragma unroll
    for (int f = 0; f < 32; ++f)
        bf[f] = *(const bf16x8*)(wb + W3B + f * 512 + lane * 8);
    float b3v[8];
#pragma unroll
    for (int jc = 0; jc < 8; ++jc) b3v[jc] = (bias + B3)[jc * 16 + l16];

    for (int it = 0; it < iters; ++it) {
        int rb = (blockIdx.x * iters + it) * 64 + wv * 16;
        if (rb >= Mtot) break;
        int p = rb + l16; if (p >= Mtot) p = Mtot - 1;
        int bl = p >> 8, i = p & 255;
        int tk = tokens[(long)(treeOff + bl) * NTOK + 255 + i];
        bf16x8 ax[4];
#pragma unroll
        for (int ks = 0; ks < 4; ++ks)
            ax[ks] = ldA(emb, (long)tk * 128 + ks * 32 + quad * 8, isbf);
        // sorted slots for the 4 output nodes (hoisted, reused across jc)
        int sp4[4], sd4[4];
#pragma unroll
        for (int r = 0; r < 4; ++r) {
            int cn = rb + quad * 4 + r;
            sp4[r] = inv7[cn >> 1]; sd4[r] = cn & 1;
        }
        f32x4 acc[8];
#pragma unroll
        for (int jc = 0; jc < 8; ++jc) acc[jc] = {0.f, 0.f, 0.f, 0.f};
#pragma unroll
        for (int jc = 0; jc < 8; ++jc)
#pragma unroll
            for (int ks = 0; ks < 4; ++ks)
                acc[jc] = MFMA(ax[ks], bf[jc * 4 + ks], acc[jc]);
#pragma unroll
        for (int jc = 0; jc < 8; ++jc)
#pragma unroll
            for (int r = 0; r < 4; ++r)
                stH2(hOut, sp4[r], sd4[r], jc * 16 + l16, f2s(tanh_(acc[jc][r] + b3v[jc])));
    }
}

// ---- unified level kernel: 512 threads, one jc per block, 72KB staged once,
//      barrier-free q-loop, ARITY-UNIFORM sorted tiles skip Uu or Ub. ----
__global__ __launch_bounds__(512, 4) void level8_mfma(
    const int* __restrict__ tokens, const int* __restrict__ arity, const void* emb,
    const float* __restrict__ ws, const short* __restrict__ hChild,
    const float* __restrict__ cChild, short* __restrict__ hOut, float* __restrict__ cOut,
    float* __restrict__ rootH, float* __restrict__ rootC,
    const int* __restrict__ perm, const int* __restrict__ invN,
    int lvl, int treeOff, int leafchild, int isRoot, int Mtot, int Mchild,
    int NBMB, int Q)
{
    __shared__ short Bs[72 * 512];          // 72 KB: full jc weight slice

    const int t = threadIdx.x;
    const int isbf = ((const int*)ws)[0];
    const int jc = blockIdx.x / NBMB;
    const int mb = blockIdx.x - jc * NBMB;
    const int wv = t >> 6, lane = t & 63, quad = lane >> 4, l16 = lane & 15;
    const int cnt = 1 << lvl, o2 = cnt - 1;
    const short* wb = (const short*)(ws + OFF_WB);
    const float* bias = ws + OFF_BIAS;
    const short* wj = wb + (long)jc * 36864;
    const int j = jc * 16 + l16;

    // stage the full 72 KB slice once
#pragma unroll
    for (int s = 0; s < 9; ++s) {
        int off = (s * 512 + t) * 8;
        stage16(wj + off, Bs + off);
    }
    __syncthreads();   // weights resident; only barrier in the kernel

    for (int q = 0; q < Q; ++q) {
        const int p0 = (mb * Q + q) * 128;
        if (p0 >= Mtot) break;

        // ---- sorted-slot row -> node via perm ----
        int row = wv * 16 + l16;
        int spos = p0 + row; if (spos >= Mtot) spos = Mtot - 1;
        int p = perm[spos];
        int bl = p >> lvl, i = p - (bl << lvl);
        int tk = tokens[(long)(treeOff + bl) * NTOK + o2 + i];

        // epilogue rows: node, arity, child c (issued early; hidden under MFMA)
        int pnode[4], arv[4]; float clv[4], crv[4];
#pragma unroll
        for (int r = 0; r < 4; ++r) {
            int se = p0 + wv * 16 + quad * 4 + r;
            if (se >= Mtot) se = Mtot - 1;
            int pe = perm[se];
            pnode[r] = pe;
            int ble = pe >> lvl, ie = pe - (ble << lvl);
            arv[r] = arity[(long)(treeOff + ble) * NINT + o2 + ie];
            if (!leafchild) {
                long crowe = (long)ble * (cnt << 1) + 2 * ie;
                clv[r] = cChild[((long)jc * Mchild + crowe) * 16 + l16];
                crv[r] = cChild[((long)jc * Mchild + crowe + 1) * 16 + l16];
            } else { clv[r] = 0.f; crv[r] = 0.f; }
        }

        // A-fragments: ah coalesced from sorted tile (no perm dependency)
        const short* hT = hChild + (((long)(p0 >> 4) + wv) << 12);
        bf16x8 ax[4], ah[8];
#pragma unroll
        for (int ks = 0; ks < 8; ++ks)
            ah[ks] = *(const bf16x8*)(hT + ks * 512 + lane * 8);
#pragma unroll
        for (int ks = 0; ks < 4; ++ks)
            ax[ks] = ldA(emb, (long)tk * 128 + ks * 32 + quad * 8, isbf);

        // tile arity flags (wave-uniform; boundary tile runs both paths)
        unsigned long long b0 = __ballot(arv[0] == 1);
        unsigned long long b1 = __ballot(arv[1] == 1);
        unsigned long long b2 = __ballot(arv[2] == 1);
        unsigned long long b3 = __ballot(arv[3] == 1);
        bool doUb = (b0 | b1 | b2 | b3) != 0ULL;
        bool doUu = (b0 & b1 & b2 & b3) != ~0ULL;

        f32x4 aW[4], aU[4], aB[5];
#pragma unroll
        for (int g = 0; g < 4; ++g) { aW[g] = {0,0,0,0}; aU[g] = {0,0,0,0}; }
#pragma unroll
        for (int g = 0; g < 5; ++g) aB[g] = {0,0,0,0};

        // Ub first (ah-dependent, hides the perm->tok->emb chain for ax)
        if (doUb) {
#pragma unroll
            for (int f = 32; f < 72; ++f) {
                bf16x8 b = *(const bf16x8*)&Bs[f * 512 + lane * 8];
                int fb = f - 32;
                aB[fb >> 3] = MFMA(ah[fb & 7], b, aB[fb >> 3]);
            }
        }
        if (doUu) {
#pragma unroll
            for (int f = 16; f < 32; ++f) {
                bf16x8 b = *(const bf16x8*)&Bs[f * 512 + lane * 8];
                aU[(f - 16) >> 2] = MFMA(ah[(f - 16) & 3], b, aU[(f - 16) >> 2]);
            }
        }
#pragma unroll
        for (int f = 0; f < 16; ++f) {
            bf16x8 b = *(const bf16x8*)&Bs[f * 512 + lane * 8];
            aW[f >> 2] = MFMA(ax[f & 3], b, aW[f >> 2]);
        }

        // biases late (uniform per jc, L2-hot)
        const float4 bw = ((const float4*)(bias + BW4))[j];
        const float4 bb = ((const float4*)(bias + BUB4))[j];
        const float  b1f = (bias + BUB1)[j];
        const float4 bu = ((const float4*)(bias + BUU4))[j];

        // ---- epilogue ----
#pragma unroll
        for (int r = 0; r < 4; ++r) {
            int se = p0 + wv * 16 + quad * 4 + r;
            bool val = (se < Mtot);
            int pc = pnode[r];
            bool bin = (arv[r] == 1);
            float w0 = aW[0][r] + bw.x;
            float w1 = aW[1][r] + bw.y;
            float w2 = aW[2][r] + bw.z;
            float w3 = aW[3][r] + bw.w;
            float pi, pf, po, pu;
            if (bin) { pi = w0 + aB[0][r] + bb.x; pf = w1 + aB[1][r] + bb.y;
                       po = w2 + aB[3][r] + bb.w; pu = w3 + aB[4][r] + b1f; }
            else     { pi = w0 + aU[0][r] + bu.x; pf = w1 + aU[1][r] + bu.y;
                       po = w2 + aU[2][r] + bu.z; pu = w3 + aU[3][r] + bu.w; }
            float cl = clv[r];
            float cr = bin ? crv[r] : 0.f;
            float frv = bin ? sigm(w1 + aB[2][r] + bb.z) : 0.f;
            float ig = sigm(pi), fg = sigm(pf), og = sigm(po), ug = tanh_(pu);
            float c = ig * ug + fg * cl + frv * cr;
            float h = og * tanh_(c);
            if (isRoot) {
                if (val) {
                    int ble = pc >> lvl;
                    rootH[(long)(treeOff + ble) * 128 + j] = h;
                    rootC[(long)(treeOff + ble) * 128 + j] = c;
                }
            } else if (val) {
                cOut[((long)jc * Mtot + pc) * 16 + l16] = c;
                stH2(hOut, invN[pc >> 1], pc & 1, j, f2s(h));
            }
        }
    }
}

// ---- output: rootH/rootC fp32 -> d_out ----
__global__ __launch_bounds__(256) void out_kernel(const float* ws, void* out)
{
    const int isbf = ((const int*)ws)[0];
    const float* rootH = ws + OFF_ROOT;
    const float* rootC = rootH + 32768;
    int t = blockIdx.x * 256 + threadIdx.x;
    float h = rootH[t], c = rootC[t];
    if (isbf) {
        ((__hip_bfloat16*)out)[t]         = __float2bfloat16(h);
        ((__hip_bfloat16*)out)[32768 + t] = __float2bfloat16(c);
    } else {
        ((float*)out)[t]         = h;
        ((float*)out)[32768 + t] = c;
    }
}

extern "C" void kernel_launch(void* const* d_in, const int* in_sizes, int n_in,
                              void* d_out, int out_size, void* d_ws, size_t ws_size,
                              hipStream_t stream)
{
    const int* tokens = (const int*)d_in[0];
    const int* arity  = (const int*)d_in[1];
    const void* emb   = d_in[2];
    const void* W     = d_in[3];
    const void* bW    = d_in[4];
    const void* Ubin  = d_in[5];
    const void* bUbin = d_in[6];
    const void* Uun   = d_in[7];
    const void* bUun  = d_in[8];

    float* ws = (float*)d_ws;

    int Bc = 256;
    while (Bc > 1 &&
           (size_t)((long)OFF_SORT + 24 + 2L * Bc * 255 + (long)Bc * PER_TREE) * 4 > ws_size)
        Bc >>= 1;
    const int nCh = 256 / Bc;
    const long offChunk = (long)OFF_SORT + 24 + 2L * Bc * 255;

    detect_kernel<<<1, 64, 0, stream>>>(W, ws);
    repack_mfma<<<128, 256, 0, stream>>>(W, bW, Ubin, bUbin, Uun, bUun, ws);

    int* permB = (int*)(ws + OFF_SORT) + 24;
    int* invB  = permB + Bc * 255;
    short* Ha = (short*)(ws + offChunk);
    short* Hb = Ha + (long)Bc * 32768;
    float* Ca = (float*)(Hb + (long)Bc * 16384);
    float* Cb = Ca + (long)Bc * 8192;
    float* rootH = ws + OFF_ROOT;
    float* rootC = rootH + 32768;

    for (int cidx = 0; cidx < nCh; ++cidx) {
        int toff = cidx * Bc;
        // arity bucket tables for this chunk (block-aggregated atomics)
        sort_zero<<<1, 32, 0, stream>>>(ws);
        sort_place<<<128, 256, 0, stream>>>(arity, ws, toff, Bc);
        {
            int Mleaf = Bc * 256;
            int NBL = (Mleaf + 63) / 64; if (NBL > 512) NBL = 512;
            int itersL = (Mleaf + NBL * 64 - 1) / (NBL * 64);
            const int* inv7 = invB + Bc * 127;
            leaf_mfma<<<NBL, 256, 0, stream>>>(tokens, emb, ws, Ha, inv7, toff, Mleaf, itersL);
        }
        for (int l = 7; l >= 0; --l) {
            int M = Bc << l;
            int Mchild = Bc << (l + 1);
            const short* hC = (l & 1) ? Ha : Hb;
            const float* cC = (l & 1) ? Ca : Cb;
            short* hO = (l & 1) ? Hb : Ha;
            float* cO = (l & 1) ? Cb : Ca;
            int lc = (l == 7) ? 1 : 0;
            int isRoot = (l == 0) ? 1 : 0;
            const int* permL = permB + Bc * ((1 << l) - 1);
            const int* invN  = (l > 0) ? invB + Bc * ((1 << (l - 1)) - 1) : invB;
            int NBM = (M + 127) / 128;
            int Q = NBM / 64; if (Q < 1) Q = 1;
            int NBMB = (NBM + Q - 1) / Q;
            level8_mfma<<<dim3(NBMB * 8), 512, 0, stream>>>(
                tokens, arity, emb, ws, hC, cC, hO, cO, rootH, rootC,
                permL, invN, l, toff, lc, isRoot, M, Mchild, NBMB, Q);
        }
    }
    out_kernel<<<128, 256, 0, stream>>>(ws, d_out);
}